// Round 11
// baseline (275.562 us; speedup 1.0000x reference)
//
#include <hip/hip_runtime.h>
#include <math.h>

// Problem constants (match reference setup_inputs()).
#define NG   256        // graphs
#define NP   256        // nodes per graph
#define NN   65536      // total nodes
#define NE   1048576    // edges
#define EPG  4096       // edges per graph
#define INF  16         // input feats
#define HID  64         // hidden
#define ZD   128        // latent dim
#define KFLAT 16384     // NP*HID

typedef _Float16 f16;
typedef f16  f16x8 __attribute__((ext_vector_type(8)));
typedef f16  f16x4 __attribute__((ext_vector_type(4)));
typedef float f32x4 __attribute__((ext_vector_type(4)));

#define XPCH 264  // LDS pitch (f16) for whole-graph 64x256 feature buffer
#define PCH  72   // LDS pitch (f16) for 64-wide staging tiles (16B-aligned rows)

// -------- fused per-graph preprocessing + dense normalized adjacency ---------
__global__ __launch_bounds__(256) void k_graph_ahat(const int* __restrict__ src,
                                                    const int* __restrict__ dst,
                                                    f16* __restrict__ Ahat) {
    __shared__ unsigned short eds[EPG];            // 8 KB
    __shared__ int cs_l[NP], cd_l[NP], cnt[NP], buf[NP];
    __shared__ float ns_l[NP], nd_l[NP];
    __shared__ unsigned char cols_l[EPG];          // 4 KB
    __shared__ float acc[32 * 256];                // 32 KB
    const int g = blockIdx.x, t = threadIdx.x;
    cs_l[t] = 0; cd_l[t] = 0;
    __syncthreads();
    for (int i = t; i < EPG; i += 256) {
        int s = src[g * EPG + i] & 255, d = dst[g * EPG + i] & 255;
        eds[i] = (unsigned short)((s << 8) | d);
        atomicAdd(&cs_l[s], 1);
        atomicAdd(&cd_l[d], 1);
    }
    __syncthreads();
    ns_l[t] = rsqrtf((float)max(cs_l[t], 1));
    nd_l[t] = rsqrtf((float)max(cd_l[t], 1));
    const int v0 = cd_l[t];
    buf[t] = v0;
    __syncthreads();
    for (int off = 1; off < NP; off <<= 1) {
        int v = (t >= off) ? buf[t - off] : 0;
        __syncthreads();
        buf[t] += v;
        __syncthreads();
    }
    const int rpl = buf[t] - v0;
    cd_l[t] = rpl;
    cnt[t] = 0;
    __syncthreads();
    for (int i = t; i < EPG; i += 256) {
        int e = eds[i], s = e >> 8, d = e & 255;
        int p = atomicAdd(&cnt[d], 1);
        cols_l[cd_l[d] + p] = (unsigned char)s;
    }
    __syncthreads();
    for (int ch = 0; ch < 8; ++ch) {
        for (int idx = t; idx < 8192; idx += 256) acc[idx] = 0.f;
        __syncthreads();
        {
            int dl = t >> 3, j = t & 7;
            int d = ch * 32 + dl;
            int e0 = cd_l[d];
            int e1 = (d < 255) ? cd_l[d + 1] : EPG;
            for (int e = e0 + j; e < e1; e += 8) {
                int s = cols_l[e];
                atomicAdd(&acc[dl * 256 + s], ns_l[s]);
            }
        }
        __syncthreads();
        for (int idx = t; idx < 8192; idx += 256) {
            int dl = idx >> 8, s = idx & 255;
            Ahat[(((size_t)(g * 256 + ch * 32 + dl)) << 8) | s] =
                (f16)(acc[idx] * nd_l[ch * 32 + dl]);
        }
        __syncthreads();
    }
}

// -------------- fused one-time casts/transposes (blockIdx ranges) ------------
__global__ __launch_bounds__(256) void k_prep(const float* __restrict__ raw,
                                              const float* __restrict__ W1,
                                              const float* __restrict__ W2,
                                              const float* __restrict__ W3,
                                              const float* __restrict__ W4,
                                              const float* __restrict__ Wg2,
                                              const float* __restrict__ Wg1,
                                              const float* __restrict__ Wmu,
                                              const float* __restrict__ Wlv,
                                              const float* __restrict__ Wdec,
                                              f16* __restrict__ rawT,
                                              f16* __restrict__ wb,
                                              f16* __restrict__ WT,
                                              f16* __restrict__ Wdpt) {
    __shared__ float lsb[4 * 2080];
    const int bx = blockIdx.x, t = threadIdx.x;
    if (bx < 1024) {                               // ---- rawT xpose (F=16)
        const int g = bx >> 2, nb = bx & 3;
        for (int idx = t; idx < 64 * 16; idx += 256) {
            int n = idx >> 4, f = idx & 15;
            lsb[n * 17 + f] = raw[((size_t)(g * 256 + nb * 64 + n)) * 16 + f];
        }
        __syncthreads();
        int f = t >> 4, n0 = (t & 15) * 4;
        f16x4 v;
        for (int j = 0; j < 4; ++j) v[j] = (f16)lsb[(n0 + j) * 17 + f];
        *(f16x4*)&rawT[((size_t)g * 16 + f) * 256 + nb * 64 + n0] = v;
    } else if (bx < 1152) {                        // ---- small weights
        int idx = (bx - 1024) * 256 + t;
        const float* srcp; int off, K2, srcK;
        if (idx < 2048)       { srcp = W1;  off = 0;     K2 = 32;  srcK = 16;  }
        else if (idx < 6144)  { srcp = W2;  off = 2048;  K2 = 64;  srcK = 64;  }
        else if (idx < 10240) { srcp = W3;  off = 6144;  K2 = 64;  srcK = 64;  }
        else if (idx < 14336) { srcp = W4;  off = 10240; K2 = 64;  srcK = 64;  }
        else if (idx < 18432) { srcp = Wg2; off = 14336; K2 = 64;  srcK = 64;  }
        else                  { srcp = Wg1; off = 18432; K2 = 224; srcK = 208; }
        int l = idx - off, of = l / K2, k = l % K2;
        wb[idx] = (k < srcK) ? (f16)srcp[k * 64 + of] : (f16)0.f;
    } else if (bx < 5248) {                        // ---- WT (Wmu|Wlv transposed)
        const int b2 = bx - 1152;
        const int kt = b2 >> 3, jt = b2 & 7;
        const int k0 = kt * 32, j0 = (jt & 3) * 32;
        const float* Wsel = (jt < 4) ? Wmu : Wlv;
        const int jl = t & 31, kl0 = t >> 5;
        for (int p = 0; p < 4; ++p) {
            int kl = kl0 + p * 8;
            lsb[kl * 33 + jl] = Wsel[(size_t)(k0 + kl) * ZD + j0 + jl];
        }
        __syncthreads();
        const int kl2 = t & 31, jl0 = t >> 5;
        for (int p = 0; p < 4; ++p) {
            int jw = jl0 + p * 8;
            WT[(size_t)(jt * 32 + jw) * KFLAT + k0 + kl2] = (f16)lsb[kl2 * 33 + jw];
        }
    } else {                                       // ---- Wdpt permute-cast
        const int b2 = bx - 5248;
        const int kc = b2 >> 3, nc = b2 & 7;
        const int k0 = kc * 4, n0 = nc * 32;
        float (*ls4)[2080] = (float(*)[2080])lsb;
        for (int idx = t; idx < 8192; idx += 256) {
            int kk = idx >> 11, jl = idx & 2047;
            ls4[kk][jl + (jl >> 6)] = Wdec[(size_t)(k0 + kk) * KFLAT + n0 * 64 + jl];
        }
        __syncthreads();
        for (int p = 0; p < 8; ++p) {
            int lin = p * 256 + t;
            int h = lin >> 5, nl = lin & 31;
            int js = nl * 65 + h;
            f16x4 v = {(f16)ls4[0][js], (f16)ls4[1][js], (f16)ls4[2][js], (f16)ls4[3][js]};
            *(f16x4*)&Wdpt[(size_t)(h * 256 + n0 + nl) * ZD + k0] = v;
        }
    }
}

// -------------------- fused encoder: 4 GraphConvs in one kernel --------------
// Grid NG, 1024 thr. Single whole-graph XY buffer (input consumed before
// overwrite); Ahat tiles register-prefetched one kc ahead (tile is conv-
// independent, so the pipeline runs across conv boundaries). LDS = 80.1 KB
// -> 2 blocks/CU (launch_bounds(1024,8), VGPR cap 64).
__global__ __launch_bounds__(1024, 8) void k_enc(const f16* __restrict__ rawT,
                                                 const f16* __restrict__ Ahat,
                                                 const f16* __restrict__ wb,
                                                 const float* __restrict__ b1,
                                                 const float* __restrict__ b2,
                                                 const float* __restrict__ b3,
                                                 const float* __restrict__ b4,
                                                 f16* __restrict__ h1t,
                                                 f16* __restrict__ h3t,
                                                 f16* __restrict__ h4b) {
    __shared__ f16 XY[64 * XPCH];      // 33.8 KB
    __shared__ f16 As[4][64 * PCH];    // 36.9 KB, aliased as Pt per group
    __shared__ f16 Ws[64 * PCH];       // 9.2 KB
    __shared__ float bs[64];
    const int g = blockIdx.x, t = threadIdx.x;
    const int wg = t >> 8, tl = t & 255, wl = (t >> 6) & 3;
    const int lane = t & 63, m16 = lane & 15, q = lane >> 4;
    const int d0 = tl >> 4, s0 = (tl * 4) & 63;    // staging coords
    const f16* abase = &Ahat[((size_t)(g * 256 + wg * 64 + d0)) * 256 + s0];
    f16x4 pre[4];
#pragma unroll
    for (int p = 0; p < 4; ++p)                    // prefetch kc=0 tile
        pre[p] = *(const f16x4*)&abase[(size_t)p * 16 * 256];
    for (int idx = t * 8; idx < 16 * 256; idx += 8192) {
        int f = idx >> 8, n = idx & 255;
        *(f16x8*)&XY[f * XPCH + n] =
            *(const f16x8*)&rawT[((size_t)g * 16 + f) * 256 + n];
    }
    const int woff[4] = {0, 2048, 6144, 10240};
    const float* bptr[4] = {b1, b2, b3, b4};
    for (int c = 0; c < 4; ++c) {
        const int MT = (c == 0) ? 1 : 4;
        const int K2 = (c == 0) ? 32 : 64;
        const f16* wt = wb + woff[c];
        if (t < 64) bs[t] = bptr[c][t];
        for (int idx = t * 4; idx < 64 * K2; idx += 4096) {
            int of = idx / K2, k = idx % K2;
            *(f16x4*)&Ws[of * PCH + k] = *(const f16x4*)&wt[of * K2 + k];
        }
        f32x4 acc1[4] = {};
        for (int kc = 0; kc < 4; ++kc) {
#pragma unroll
            for (int p = 0; p < 4; ++p)            // commit prefetched tile
                *(f16x4*)&As[wg][(d0 + 16 * p) * PCH + s0] = pre[p];
            const int nkc = (kc + 1) & 3;          // next tile (wraps to next conv)
#pragma unroll
            for (int p = 0; p < 4; ++p)
                pre[p] = *(const f16x4*)&abase[(size_t)p * 16 * 256 + nkc * 64];
            __syncthreads();
#pragma unroll
            for (int ks = 0; ks < 2; ++ks) {
                f16x8 b = *(const f16x8*)&As[wg][(wl * 16 + m16) * PCH + ks * 32 + q * 8];
                for (int mt = 0; mt < MT; ++mt) {
                    f16x8 a = *(const f16x8*)&XY[(mt * 16 + m16) * XPCH + kc * 64 + ks * 32 + q * 8];
                    acc1[mt] = __builtin_amdgcn_mfma_f32_16x16x32_f16(a, b, acc1[mt], 0, 0, 0);
                }
            }
            __syncthreads();
        }
        // stage 2: (agg)@W via Pt = As[wg]
        {
            f16* Pt = As[wg];
            if (MT == 1)
                for (int idx = tl; idx < 1024; idx += 256)
                    Pt[(idx >> 4) * PCH + 16 + (idx & 15)] = (f16)0.f;
            for (int mt = 0; mt < MT; ++mt) {
                f16x4 v = {(f16)acc1[mt][0], (f16)acc1[mt][1],
                           (f16)acc1[mt][2], (f16)acc1[mt][3]};
                *(f16x4*)&Pt[(wl * 16 + m16) * PCH + mt * 16 + q * 4] = v;
            }
            __syncthreads();
            f32x4 acc2[4] = {};
            for (int ks = 0; ks < K2 / 32; ++ks) {
                f16x8 b = *(const f16x8*)&Pt[(wl * 16 + m16) * PCH + ks * 32 + q * 8];
#pragma unroll
                for (int mt = 0; mt < 4; ++mt) {
                    f16x8 a = *(const f16x8*)&Ws[(mt * 16 + m16) * PCH + ks * 32 + q * 8];
                    acc2[mt] = __builtin_amdgcn_mfma_f32_16x16x32_f16(a, b, acc2[mt], 0, 0, 0);
                }
            }
#pragma unroll
            for (int mt = 0; mt < 4; ++mt)
#pragma unroll
                for (int r = 0; r < 4; ++r) {
                    int of = mt * 16 + q * 4 + r;
                    float v = fmaxf(acc2[mt][r] + bs[of], 0.f);
                    XY[of * XPCH + wg * 64 + wl * 16 + m16] = (f16)v;
                }
        }
        __syncthreads();
        if (c == 0) {
            for (int idx = t * 8; idx < 64 * 256; idx += 8192) {
                int of = idx >> 8, n = idx & 255;
                *(f16x8*)&h1t[((size_t)g * 64 + of) * 256 + n] =
                    *(const f16x8*)&XY[of * XPCH + n];
            }
        } else if (c == 2) {
            for (int idx = t * 8; idx < 64 * 256; idx += 8192) {
                int of = idx >> 8, n = idx & 255;
                *(f16x8*)&h3t[((size_t)g * 64 + of) * 256 + n] =
                    *(const f16x8*)&XY[of * XPCH + n];
            }
        } else if (c == 3) {
            int n = (t >> 2) & 255, of0 = (t & 3) * 16;
            f16x8 v0, v1;
            for (int i = 0; i < 8; ++i) v0[i] = XY[(of0 + i) * XPCH + n];
            for (int i = 0; i < 8; ++i) v1[i] = XY[(of0 + 8 + i) * XPCH + n];
            size_t base = ((size_t)(g * 256 + n)) * 64 + of0;
            *(f16x8*)&h4b[base] = v0;
            *(f16x8*)&h4b[base + 8] = v1;
        }
    }
}

// ------------------------------------- mu/logvar MFMA split-K GEMM -----------
#define BKP 136
__global__ __launch_bounds__(256) void k_mulv_mfma(const f16* __restrict__ h4b,
                                                   const f16* __restrict__ WT,
                                                   float* __restrict__ part) {
    __shared__ f16 Ab[64 * BKP];
    __shared__ f16 Bb[64 * BKP];
    const int bx = blockIdx.x;
    const int kc = bx & 63, jt = (bx >> 6) & 3, gt = bx >> 8;
    const int t = threadIdx.x;
    const int w = t >> 6, lane = t & 63;
    const int m16 = lane & 15, q = lane >> 4;
    f32x4 acc[4] = {};
    const int k0base = kc * 256;
    for (int ks = 0; ks < 2; ++ks) {
        const int k0 = k0base + ks * 128;
#pragma unroll
        for (int p = 0; p < 4; ++p) {
            int oct = t + p * 256;
            int r = oct >> 4, c8 = oct & 15;
            *(f16x8*)&Ab[r * BKP + c8 * 8] =
                *(const f16x8*)&h4b[(size_t)(gt * 64 + r) * KFLAT + k0 + c8 * 8];
            *(f16x8*)&Bb[r * BKP + c8 * 8] =
                *(const f16x8*)&WT[(size_t)(jt * 64 + r) * KFLAT + k0 + c8 * 8];
        }
        __syncthreads();
#pragma unroll
        for (int kk = 0; kk < 4; ++kk) {
            f16x8 a = *(const f16x8*)&Ab[(w * 16 + m16) * BKP + kk * 32 + q * 8];
#pragma unroll
            for (int nt = 0; nt < 4; ++nt) {
                f16x8 b = *(const f16x8*)&Bb[(nt * 16 + m16) * BKP + kk * 32 + q * 8];
                acc[nt] = __builtin_amdgcn_mfma_f32_16x16x32_f16(a, b, acc[nt], 0, 0, 0);
            }
        }
        __syncthreads();
    }
    const int pb = kc << 16;
#pragma unroll
    for (int nt = 0; nt < 4; ++nt) {
        const int jj = jt * 64 + nt * 16 + m16;
#pragma unroll
        for (int r = 0; r < 4; ++r) {
            int g = gt * 64 + w * 16 + q * 4 + r;
            part[pb + g * 256 + jj] = acc[nt][r];
        }
    }
}

// reduce partials -> mu, logvar (d_out) and z (f16).
__global__ __launch_bounds__(256) void k_reduce(const float* __restrict__ part,
                                                const float* __restrict__ bmu,
                                                const float* __restrict__ blv,
                                                const float* __restrict__ eps,
                                                float* __restrict__ out,
                                                f16* __restrict__ zb) {
    const int idx = blockIdx.x * 256 + threadIdx.x;
    const int g = idx >> 7, j = idx & 127;
    float mu = bmu[j], lv = blv[j];
    for (int kc = 0; kc < 64; ++kc) {
        mu += part[(kc << 16) + g * 256 + j];
        lv += part[(kc << 16) + g * 256 + 128 + j];
    }
    out[1048576 + idx] = mu;
    out[1048576 + 32768 + idx] = lv;
    zb[idx] = (f16)(mu + eps[idx] * expf(0.5f * lv));
}

// ----------- latt[g][h*256+n] = (z @ Wdec)[g][n*64+h] + bdec, via MFMA -------
#define DKP 136
__global__ __launch_bounds__(256) void k_decgemm(const f16* __restrict__ zb,
                                                 const f16* __restrict__ Wdpt,
                                                 const float* __restrict__ bdec,
                                                 f16* __restrict__ latt) {
    __shared__ f16 Az[64 * DKP];
    __shared__ f16 Bz[128 * DKP];
    const int gt = blockIdx.x >> 7, jt = blockIdx.x & 127;   // grid 512
    const int t = threadIdx.x, w = t >> 6, lane = t & 63, m16 = lane & 15, q = lane >> 4;
    for (int idx = t * 8; idx < 64 * 128; idx += 2048) {
        int r = idx >> 7, c = idx & 127;
        *(f16x8*)&Az[r * DKP + c] = *(const f16x8*)&zb[(gt * 64 + r) * ZD + c];
    }
    for (int idx = t * 8; idx < 128 * 128; idx += 2048) {
        int r = idx >> 7, c = idx & 127;
        *(f16x8*)&Bz[r * DKP + c] = *(const f16x8*)&Wdpt[((size_t)jt * 128 + r) * ZD + c];
    }
    __syncthreads();
    f32x4 acc[4][2] = {};
#pragma unroll
    for (int kk = 0; kk < 4; ++kk) {
        f16x8 b0 = *(const f16x8*)&Bz[(w * 32 + m16) * DKP + kk * 32 + q * 8];
        f16x8 b1 = *(const f16x8*)&Bz[(w * 32 + 16 + m16) * DKP + kk * 32 + q * 8];
#pragma unroll
        for (int mt = 0; mt < 4; ++mt) {
            f16x8 a = *(const f16x8*)&Az[(mt * 16 + m16) * DKP + kk * 32 + q * 8];
            acc[mt][0] = __builtin_amdgcn_mfma_f32_16x16x32_f16(a, b0, acc[mt][0], 0, 0, 0);
            acc[mt][1] = __builtin_amdgcn_mfma_f32_16x16x32_f16(a, b1, acc[mt][1], 0, 0, 0);
        }
    }
#pragma unroll
    for (int nt = 0; nt < 2; ++nt) {
        int jg = jt * 128 + w * 32 + nt * 16 + m16;
        int h = jg >> 8, n = jg & 255;
        float bd = bdec[n * 64 + h];
#pragma unroll
        for (int mt = 0; mt < 4; ++mt)
#pragma unroll
            for (int r = 0; r < 4; ++r) {
                int gg = gt * 64 + mt * 16 + q * 4 + r;
                latt[(size_t)gg * KFLAT + jg] = (f16)(acc[mt][nt][r] + bd);
            }
    }
}

// ----------------- fused decoder: catgemm, g1, g2, out GEMM ------------------
#define PB 40
__global__ __launch_bounds__(1024) void k_decfused(const f16* __restrict__ latt,
                                                   const f16* __restrict__ rawT,
                                                   const f16* __restrict__ h1t,
                                                   const f16* __restrict__ h3t,
                                                   const f16* __restrict__ Ahat,
                                                   const f16* __restrict__ wb,
                                                   const float* __restrict__ bg1,
                                                   const float* __restrict__ bg2,
                                                   const float* __restrict__ Wout,
                                                   const float* __restrict__ bout,
                                                   const float* __restrict__ raw,
                                                   float* __restrict__ out) {
    __shared__ f16 XY[2][64 * XPCH];   // 67.6 KB
    __shared__ f16 As[4][64 * PCH];    // 36.9 KB
    __shared__ f16 Ws[64 * PCH];
    __shared__ f16 Wsb[64 * PB];
    __shared__ f16 Bt[4][64 * PB];
    __shared__ float WL[1024];
    __shared__ float bs[64];
    const int g = blockIdx.x, t = threadIdx.x;
    const int wg = t >> 8, tl = t & 255, wl = (t >> 6) & 3;
    const int lane = t & 63, m16 = lane & 15, q = lane >> 4;
    const f16* wg1t = wb + 18432;
    const f16* wg2t = wb + 14336;
    const int d0 = tl >> 4, s0 = (tl * 4) & 63;
    const f16* abase = &Ahat[((size_t)(g * 256 + wg * 64 + d0)) * 256 + s0];
    f16x4 pre[4];
#pragma unroll
    for (int p = 0; p < 4; ++p)                    // prefetch Ahat kc=0 for phase 2
        pre[p] = *(const f16x4*)&abase[(size_t)p * 16 * 256];

    auto load_bt = [&](int kc) -> f16x8 {          // cat^T row slice for Bt staging
        int kin = kc * 32 + (tl >> 3);
        const f16* sp = nullptr;
        if (kin < 64)       sp = latt + ((size_t)g * 64 + kin) * 256;
        else if (kin < 80)  sp = rawT + ((size_t)g * 16 + (kin - 64)) * 256;
        else if (kin < 144) sp = h1t  + ((size_t)g * 64 + (kin - 80)) * 256;
        else if (kin < 208) sp = h3t  + ((size_t)g * 64 + (kin - 144)) * 256;
        f16x8 v = {};
        if (sp) v = *(const f16x8*)&sp[wg * 64 + (tl & 7) * 8];
        return v;
    };
    auto load_wsb = [&](int kc) -> f16x4 {
        f16x4 v = {};
        if (t < 512) v = *(const f16x4*)&wg1t[(t >> 3) * 224 + kc * 32 + ((t * 4) & 31)];
        return v;
    };
    // ---- phase 1: t^T = Wg1t . cat^T -> XY[0] (register-prefetched staging)
    {
        f16x8 bv = load_bt(0);
        f16x4 wv = load_wsb(0);
        f32x4 acc[4] = {};
        for (int kc = 0; kc < 7; ++kc) {
            if (t < 512) *(f16x4*)&Wsb[(t >> 3) * PB + ((t * 4) & 31)] = wv;
            {
                int kr = tl >> 3, n8 = (tl & 7) * 8;
                for (int i = 0; i < 8; ++i) Bt[wg][(n8 + i) * PB + kr] = bv[i];
            }
            if (kc < 6) { bv = load_bt(kc + 1); wv = load_wsb(kc + 1); }
            __syncthreads();
            f16x8 b = *(const f16x8*)&Bt[wg][(wl * 16 + m16) * PB + q * 8];
#pragma unroll
            for (int mt = 0; mt < 4; ++mt) {
                f16x8 a = *(const f16x8*)&Wsb[(mt * 16 + m16) * PB + q * 8];
                acc[mt] = __builtin_amdgcn_mfma_f32_16x16x32_f16(a, b, acc[mt], 0, 0, 0);
            }
            __syncthreads();
        }
#pragma unroll
        for (int mt = 0; mt < 4; ++mt)
#pragma unroll
            for (int r = 0; r < 4; ++r)
                XY[0][(mt * 16 + q * 4 + r) * XPCH + wg * 64 + wl * 16 + m16] =
                    (f16)acc[mt][r];
        __syncthreads();
    }
    // ---- phase 2: x1 = relu(Ahat @ t + bg1) -> XY[1] (gather-only)
    {
        if (t < 64) bs[t] = bg1[t];
        f32x4 acc1[4] = {};
        for (int kc = 0; kc < 4; ++kc) {
#pragma unroll
            for (int p = 0; p < 4; ++p)
                *(f16x4*)&As[wg][(d0 + 16 * p) * PCH + s0] = pre[p];
            const int nkc = (kc + 1) & 3;          // wraps to kc=0 for phase 3
#pragma unroll
            for (int p = 0; p < 4; ++p)
                pre[p] = *(const f16x4*)&abase[(size_t)p * 16 * 256 + nkc * 64];
            __syncthreads();
#pragma unroll
            for (int ks = 0; ks < 2; ++ks) {
                f16x8 b = *(const f16x8*)&As[wg][(wl * 16 + m16) * PCH + ks * 32 + q * 8];
#pragma unroll
                for (int mt = 0; mt < 4; ++mt) {
                    f16x8 a = *(const f16x8*)&XY[0][(mt * 16 + m16) * XPCH + kc * 64 + ks * 32 + q * 8];
                    acc1[mt] = __builtin_amdgcn_mfma_f32_16x16x32_f16(a, b, acc1[mt], 0, 0, 0);
                }
            }
            __syncthreads();
        }
#pragma unroll
        for (int mt = 0; mt < 4; ++mt)
#pragma unroll
            for (int r = 0; r < 4; ++r) {
                int of = mt * 16 + q * 4 + r;
                float v = fmaxf(acc1[mt][r] + bs[of], 0.f);
                XY[1][of * XPCH + wg * 64 + wl * 16 + m16] = (f16)v;
            }
        __syncthreads();
    }
    // ---- phase 3: x2 = relu((Ahat @ x1)@Wg2 + bg2) -> XY[0]
    {
        if (t < 64) bs[t] = bg2[t];
        for (int idx = t * 4; idx < 4096; idx += 4096) {
            int of = idx >> 6, k = idx & 63;
            *(f16x4*)&Ws[of * PCH + k] = *(const f16x4*)&wg2t[of * 64 + k];
        }
        f32x4 acc1[4] = {};
        for (int kc = 0; kc < 4; ++kc) {
#pragma unroll
            for (int p = 0; p < 4; ++p)
                *(f16x4*)&As[wg][(d0 + 16 * p) * PCH + s0] = pre[p];
            if (kc < 3) {
#pragma unroll
                for (int p = 0; p < 4; ++p)
                    pre[p] = *(const f16x4*)&abase[(size_t)p * 16 * 256 + (kc + 1) * 64];
            }
            __syncthreads();
#pragma unroll
            for (int ks = 0; ks < 2; ++ks) {
                f16x8 b = *(const f16x8*)&As[wg][(wl * 16 + m16) * PCH + ks * 32 + q * 8];
#pragma unroll
                for (int mt = 0; mt < 4; ++mt) {
                    f16x8 a = *(const f16x8*)&XY[1][(mt * 16 + m16) * XPCH + kc * 64 + ks * 32 + q * 8];
                    acc1[mt] = __builtin_amdgcn_mfma_f32_16x16x32_f16(a, b, acc1[mt], 0, 0, 0);
                }
            }
            __syncthreads();
        }
        f16* Pt = As[wg];
#pragma unroll
        for (int mt = 0; mt < 4; ++mt) {
            f16x4 v = {(f16)acc1[mt][0], (f16)acc1[mt][1],
                       (f16)acc1[mt][2], (f16)acc1[mt][3]};
            *(f16x4*)&Pt[(wl * 16 + m16) * PCH + mt * 16 + q * 4] = v;
        }
        __syncthreads();
        f32x4 acc2[4] = {};
#pragma unroll
        for (int ks = 0; ks < 2; ++ks) {
            f16x8 b = *(const f16x8*)&Pt[(wl * 16 + m16) * PCH + ks * 32 + q * 8];
#pragma unroll
            for (int mt = 0; mt < 4; ++mt) {
                f16x8 a = *(const f16x8*)&Ws[(mt * 16 + m16) * PCH + ks * 32 + q * 8];
                acc2[mt] = __builtin_amdgcn_mfma_f32_16x16x32_f16(a, b, acc2[mt], 0, 0, 0);
            }
        }
#pragma unroll
        for (int mt = 0; mt < 4; ++mt)
#pragma unroll
            for (int r = 0; r < 4; ++r) {
                int of = mt * 16 + q * 4 + r;
                float v = fmaxf(acc2[mt][r] + bs[of], 0.f);
                XY[0][of * XPCH + wg * 64 + wl * 16 + m16] = (f16)v;
            }
        __syncthreads();
    }
    // ---- phase 4: recon = x2^T @ Wout + bout (col0 = raw)
    {
        WL[t & 1023] = Wout[t & 1023];
        __syncthreads();
        int n = t & 255, og = t >> 8;
        float acc4[4];
        for (int j = 0; j < 4; ++j) acc4[j] = bout[og * 4 + j];
#pragma unroll 4
        for (int f = 0; f < 64; ++f) {
            float xv = (float)XY[0][f * XPCH + n];
            for (int j = 0; j < 4; ++j) acc4[j] += xv * WL[f * 16 + og * 4 + j];
        }
        size_t ob = ((size_t)(g * 256 + n)) * 16 + og * 4;
        if (og == 0) acc4[0] = raw[((size_t)(g * 256 + n)) * 16];
        *(float4*)&out[ob] = make_float4(acc4[0], acc4[1], acc4[2], acc4[3]);
    }
}

// ----------------------------------------------------------------- launch ----
extern "C" void kernel_launch(void* const* d_in, const int* in_sizes, int n_in,
                              void* d_out, int out_size, void* d_ws, size_t ws_size,
                              hipStream_t stream) {
    const float* raw  = (const float*)d_in[0];
    const int*   src  = (const int*)d_in[1];
    const int*   dst  = (const int*)d_in[2];
    const float* eps  = (const float*)d_in[3];
    const float* W1   = (const float*)d_in[4];
    const float* b1   = (const float*)d_in[5];
    const float* W2   = (const float*)d_in[6];
    const float* b2   = (const float*)d_in[7];
    const float* W3   = (const float*)d_in[8];
    const float* b3   = (const float*)d_in[9];
    const float* W4   = (const float*)d_in[10];
    const float* b4   = (const float*)d_in[11];
    const float* Wmu  = (const float*)d_in[12];
    const float* bmu  = (const float*)d_in[13];
    const float* Wlv  = (const float*)d_in[14];
    const float* blv  = (const float*)d_in[15];
    const float* Wdec = (const float*)d_in[16];
    const float* bdec = (const float*)d_in[17];
    const float* Wg1  = (const float*)d_in[18];
    const float* bg1  = (const float*)d_in[19];
    const float* Wg2  = (const float*)d_in[20];
    const float* bg2  = (const float*)d_in[21];
    const float* Wout = (const float*)d_in[22];
    const float* bout = (const float*)d_in[23];
    float* out = (float*)d_out;

    // workspace carve-up (~95 MB)
    char* p = (char*)d_ws;
    f16* Ahat = (f16*)p;              p += (size_t)NG * 256 * 256 * 2;   // 32 MB
    f16* WT   = (f16*)p;              p += (size_t)256 * KFLAT * 2;      // 8 MB
    f16* Wdpt = (f16*)p;              p += (size_t)KFLAT * ZD * 2;       // 4 MB
    f16* wb   = (f16*)p;              p += 65536;                        // 64 KB
    f16* zb   = (f16*)p;              p += 65536;                        // 64 KB
    f16* rawT = (f16*)p;              p += (size_t)NG * 16 * 256 * 2;    // 2 MB
    f16* h1t  = (f16*)p;              p += (size_t)NN * 64 * 2;          // 8 MB
    f16* h3t  = (f16*)p;              p += (size_t)NN * 64 * 2;
    f16* h4b  = (f16*)p;              p += (size_t)NN * 64 * 2;
    f16* latt = (f16*)p;              p += (size_t)NN * 64 * 2;
    float* part = (float*)p;          p += (size_t)64 * 65536 * 4;       // 16 MB

    // preprocessing (2 launches)
    k_graph_ahat<<<NG, 256, 0, stream>>>(src, dst, Ahat);
    k_prep<<<5504, 256, 0, stream>>>(raw, W1, W2, W3, W4, Wg2, Wg1, Wmu, Wlv, Wdec,
                                     rawT, wb, WT, Wdpt);

    // encoder (1 launch: conv1..conv4 fused)
    k_enc<<<NG, 1024, 0, stream>>>(rawT, Ahat, wb, b1, b2, b3, b4, h1t, h3t, h4b);

    // bottleneck: mu/logvar -> z -> latent
    k_mulv_mfma<<<1024, 256, 0, stream>>>(h4b, WT, part);
    k_reduce<<<128, 256, 0, stream>>>(part, bmu, blv, eps, out, zb);
    k_decgemm<<<512, 256, 0, stream>>>(zb, Wdpt, bdec, latt);

    // decoder (1 launch: catgemm + g1 + g2 + out GEMM fused)
    k_decfused<<<NG, 1024, 0, stream>>>(latt, rawT, h1t, h3t, Ahat, wb,
                                        bg1, bg2, Wout, bout, raw, out);
}